// Round 1
// baseline (29038.245 us; speedup 1.0000x reference)
//
#include <hip/hip_runtime.h>

// ---------------------------------------------------------------------------
// GRUNet: one flattened 8192-step 2-layer GRU scan (phase 1), a 256-step
// 2-layer GRU scan over sampled states (phase 2), then 2 tiny FCs -> 2 floats.
// Strategy: persistent kernel, 256 WGs (one per CU), each WG owns 4 h-elems.
// Cross-WG broadcast+sync per step via 16B {data,tag} records stored/loaded
// with agent-scope (sc1) vector ops through the Infinity Cache.
// Recurrent weights are register-resident packed f16, MACs via v_dot2_f32_f16.
// ---------------------------------------------------------------------------

typedef unsigned u32x4 __attribute__((ext_vector_type(4)));
typedef unsigned u32x2 __attribute__((ext_vector_type(2)));
typedef _Float16 h2_t  __attribute__((ext_vector_type(2)));

#define NWG 256

// persistent device state (re-initialized every call by init_recs)
__device__ u32x4    g_recL0[2][NWG];     // layer-0 h records: {pair0,pair1,tag,0}
__device__ u32x4    g_recL1[2][NWG];     // layer-1 h records
__device__ unsigned g_seq2[256][512];    // sampled states (f16 pairs) for gru2

// ---- f16 pack/unpack (RNE) ----
__device__ __forceinline__ unsigned pk(float a, float b) {
  unsigned short ua = __builtin_bit_cast(unsigned short, (_Float16)a);
  unsigned short ub = __builtin_bit_cast(unsigned short, (_Float16)b);
  return (unsigned)ua | ((unsigned)ub << 16);
}
__device__ __forceinline__ float unpk(unsigned u, int hi) {
  unsigned short us = (unsigned short)(hi ? (u >> 16) : (u & 0xffffu));
  return (float)__builtin_bit_cast(_Float16, us);
}

// ---- dot2: f16x2 * f16x2 + f32 ----
#if __has_builtin(__builtin_amdgcn_fdot2)
__device__ __forceinline__ float fdot2(unsigned a, unsigned b, float c) {
  return __builtin_amdgcn_fdot2(__builtin_bit_cast(h2_t, a),
                                __builtin_bit_cast(h2_t, b), c, false);
}
#else
__device__ __forceinline__ float fdot2(unsigned a, unsigned b, float c) {
  h2_t ha = __builtin_bit_cast(h2_t, a), hb = __builtin_bit_cast(h2_t, b);
  return c + (float)ha[0] * (float)hb[0] + (float)ha[1] * (float)hb[1];
}
#endif

// ---- agent-scope (coherent-at-L3) vector load/store ----
__device__ __forceinline__ u32x4 ld_sc_v4(const u32x4* p) {
  u32x4 v;
  asm volatile("global_load_dwordx4 %0, %1, off sc1\n\t"
               "s_waitcnt vmcnt(0)"
               : "=&v"(v) : "v"(p) : "memory");
  return v;
}
__device__ __forceinline__ void ld_sc_2x4(const u32x4* p0, const u32x4* p1,
                                          u32x4& a, u32x4& b) {
  asm volatile("global_load_dwordx4 %0, %2, off sc1\n\t"
               "global_load_dwordx4 %1, %3, off sc1\n\t"
               "s_waitcnt vmcnt(0)"
               : "=&v"(a), "=&v"(b) : "v"(p0), "v"(p1) : "memory");
}
__device__ __forceinline__ void st_sc_v4(u32x4* p, u32x4 v) {
  asm volatile("global_store_dwordx4 %0, %1, off sc1"
               :: "v"(p), "v"(v) : "memory");
}
__device__ __forceinline__ void st_sc_v2(void* p, u32x2 v) {
  asm volatile("global_store_dwordx2 %0, %1, off sc1"
               :: "v"(p), "v"(v) : "memory");
}

__device__ __forceinline__ float sigf(float x) { return 1.f / (1.f + __expf(-x)); }

// ---- LDS swizzles (16B-chunk XOR) ----
// 512-u32 buffers (h vectors / phase-2 x): chunk ch -> ch ^ ((ch>>3)&7)
__device__ __forceinline__ int swzH_pos(int idx) {
  int ch = idx >> 2;
  ch ^= (ch >> 3) & 7;
  return (ch << 2) | (idx & 3);
}
// 256-u32 buffer (phase-1 x): chunk ch -> ch ^ ((ch>>2)&7)
__device__ __forceinline__ int swzX_pos(int idx) {
  int ch = idx >> 2;
  ch ^= (ch >> 2) & 7;
  return (ch << 2) | (idx & 3);
}

__global__ void init_recs() {
  int t = blockIdx.x * blockDim.x + threadIdx.x;  // <<<4,256>>> = 1024
  u32x4 ff = {0u, 0u, 0xFFFFFFFFu, 0u};           // tag never matches a step
  if (t < 512)       g_recL0[t >> 8][t & 255] = ff;
  else               g_recL1[(t - 512) >> 8][t & 255] = ff;
}

// PHASE 1: gru1 over 8192 flat steps (layer0 input = x, 512 cols)
// PHASE 2: gru2 over 256 steps (layer0 input = g_seq2, 1024 cols) + FC tail
// Matrices: m0=Wh_l0, m1=Wi_l1, m2=Wh_l1, m3=Wi_l0.  Waves 0..3 own m0..m3.
template <int PHASE>
__global__ __launch_bounds__(256, 1) void gru_phase(
    const float* __restrict__ Wm0, const float* __restrict__ Wm1,
    const float* __restrict__ Wm2, const float* __restrict__ Wm3,
    const float* __restrict__ bh0, const float* __restrict__ bi1,
    const float* __restrict__ bh1, const float* __restrict__ bi0,
    const float* __restrict__ x,
    const float* __restrict__ fc1W, const float* __restrict__ fc1b,
    const float* __restrict__ fc2W, const float* __restrict__ fc2b,
    float* __restrict__ out)
{
  constexpr int N0 = (PHASE == 1) ? 8192 : 256;   // flat steps of layer 0
  constexpr int XC = (PHASE == 1) ? 512 : 1024;   // cols of Wm3 (Wi_l0)

  const int wg   = blockIdx.x;          // owns h elements [4*wg, 4*wg+4)
  const int tid  = threadIdx.x;
  const int wave = tid >> 6;
  const int lane = tid & 63;
  const int g4   = lane >> 4;           // quarter-wave group
  const int q    = lane & 15;           // position in 16-lane group
  const int j0   = wg * 4;

  __shared__ __attribute__((aligned(16))) unsigned sH0[2][512]; // h0[s-1], f16 pairs
  __shared__ __attribute__((aligned(16))) unsigned sH1[2][512]; // h1[s-2]
  __shared__ __attribute__((aligned(16))) unsigned sX [2][512]; // layer-0 input
  __shared__ float sD[2][48];                                   // row dots (m*12+g*4+i)
  __shared__ float sY[128];                                     // FC hidden (phase 2)

  // ---- load this wave's weight rows into registers as packed f16 ----
  // group (wave,g4) handles rows rr = g4*3+t (t<3) of matrix `wave`;
  // global row R = (rr>>2)*1024 + j0 + (rr&3); lane q handles col pairs
  // [32q,32q+32) (1024-col) or [16q,16q+16) (512-col).
  unsigned wreg[96];
  {
    const float* Wm = (wave == 0) ? Wm0 : (wave == 1) ? Wm1
                    : (wave == 2) ? Wm2 : Wm3;
    #pragma unroll
    for (int t = 0; t < 3; ++t) {
      const int rr = g4 * 3 + t;
      const int R  = (rr >> 2) * 1024 + j0 + (rr & 3);
      if (PHASE == 1 && wave == 3) {
        const float2* rp = (const float2*)(Wm + (size_t)R * XC + 32 * q);
        #pragma unroll
        for (int p = 0; p < 16; ++p) { float2 v = rp[p]; wreg[t*32 + p] = pk(v.x, v.y); }
      } else {
        const float2* rp = (const float2*)(Wm + (size_t)R * ((wave == 3) ? XC : 1024) + 64 * q);
        #pragma unroll
        for (int p = 0; p < 32; ++p) { float2 v = rp[p]; wreg[t*32 + p] = pk(v.x, v.y); }
      }
    }
  }

  // ---- per-lane gate biases for the combine step (wave 0 uses them) ----
  float bI[3], bH[3];
  {
    const int i = lane & 3, layer = (lane >> 2) & 1;
    const float* pbi = layer ? bi1 : bi0;
    const float* pbh = layer ? bh1 : bh0;
    #pragma unroll
    for (int g = 0; g < 3; ++g) {
      bI[g] = pbi[g * 1024 + j0 + i];
      bH[g] = pbh[g * 1024 + j0 + i];
    }
  }

  // =======================  serial scan  =======================
  for (int s = 0; s <= N0; ++s) {
    const int par = s & 1;

    // issue layer-0 input fetch early (independent of h)
    float2 xv = {0.f, 0.f};
    unsigned xs0 = 0, xs1 = 0;
    if (PHASE == 1) {
      if (s < N0) {
        const int b = s & 63, tt = s >> 6;  // flat step s = tt*64 + b
        xv = ((const float2*)(x + (size_t)(b * 128 + tt) * 512))[tid];
      }
    } else {
      if (s < N0) { xs0 = g_seq2[s][2 * tid]; xs1 = g_seq2[s][2 * tid + 1]; }
    }

    // poll records of step s-1 (data rides along with the tag)
    unsigned d00 = 0, d01 = 0, d10 = 0, d11 = 0;
    if (s > 0) {
      const unsigned want = (unsigned)(s - 1);
      const u32x4* a0 = &g_recL0[(s - 1) & 1][tid];
      const u32x4* a1 = &g_recL1[(s - 1) & 1][tid];
      u32x4 r0, r1;
      ld_sc_2x4(a0, a1, r0, r1);
      while (r0[2] != want || r1[2] != want) {
        __builtin_amdgcn_s_sleep(1);
        ld_sc_2x4(a0, a1, r0, r1);
      }
      d00 = r0[0]; d01 = r0[1]; d10 = r1[0]; d11 = r1[1];
    }
    // stage into LDS (swizzled)
    sH0[par][swzH_pos(2 * tid)]     = d00;
    sH0[par][swzH_pos(2 * tid + 1)] = d01;
    sH1[par][swzH_pos(2 * tid)]     = d10;
    sH1[par][swzH_pos(2 * tid + 1)] = d11;
    if (PHASE == 1) {
      if (s < N0) sX[par][swzX_pos(tid)] = pk(xv.x, xv.y);
    } else {
      if (s < N0) {
        sX[par][swzH_pos(2 * tid)]     = xs0;
        sX[par][swzH_pos(2 * tid + 1)] = xs1;
      }
    }
    __syncthreads();

    // ---- 48 row dots (register weights x LDS f16 operand) ----
    float acc0 = 0.f, acc1 = 0.f, acc2 = 0.f;
    if (PHASE == 1 && wave == 3) {               // Wi_l0: 512 cols
      const u32x4* Xv = (const u32x4*)sX[par];
      #pragma unroll
      for (int k = 0; k < 4; ++k) {
        u32x4 h4 = Xv[(4 * q + k) ^ (q & 7)];
        #pragma unroll
        for (int u = 0; u < 4; ++u) {
          const int p = 4 * k + u;
          acc0 = fdot2(wreg[p],      h4[u], acc0);
          acc1 = fdot2(wreg[32 + p], h4[u], acc1);
          acc2 = fdot2(wreg[64 + p], h4[u], acc2);
        }
      }
    } else {                                     // 1024-col matvecs
      const unsigned* hb = (wave == 2) ? sH1[par] : (wave == 3) ? sX[par] : sH0[par];
      const u32x4* Hv = (const u32x4*)hb;
      #pragma unroll
      for (int k = 0; k < 8; ++k) {
        u32x4 h4 = Hv[8 * q + (k ^ (q & 7))];
        #pragma unroll
        for (int u = 0; u < 4; ++u) {
          const int p = 4 * k + u;
          acc0 = fdot2(wreg[p],      h4[u], acc0);
          acc1 = fdot2(wreg[32 + p], h4[u], acc1);
          acc2 = fdot2(wreg[64 + p], h4[u], acc2);
        }
      }
    }
    // 16-lane reduction
    acc0 += __shfl_xor(acc0, 8, 16); acc0 += __shfl_xor(acc0, 4, 16);
    acc0 += __shfl_xor(acc0, 2, 16); acc0 += __shfl_xor(acc0, 1, 16);
    acc1 += __shfl_xor(acc1, 8, 16); acc1 += __shfl_xor(acc1, 4, 16);
    acc1 += __shfl_xor(acc1, 2, 16); acc1 += __shfl_xor(acc1, 1, 16);
    acc2 += __shfl_xor(acc2, 8, 16); acc2 += __shfl_xor(acc2, 4, 16);
    acc2 += __shfl_xor(acc2, 2, 16); acc2 += __shfl_xor(acc2, 1, 16);
    if (q < 3) {
      const float dv = (q == 0) ? acc0 : (q == 1) ? acc1 : acc2;
      sD[par][wave * 12 + g4 * 3 + q] = dv;
    }
    __syncthreads();

    // ---- gate combine + record store (wave 0; lanes replicate 8 results) ----
    if (wave == 0) {
      const int i = lane & 3;
      const int layer = (lane >> 2) & 1;
      const float* Sd = sD[par];
      const int mI = layer ? 12 : 36;   // Wi_l1 : Wi_l0 dots
      const int mH = layer ? 24 : 0;    // Wh_l1 : Wh_l0 dots
      const float pr  = Sd[mI + 0 + i] + bI[0] + Sd[mH + 0 + i] + bH[0];
      const float pz  = Sd[mI + 4 + i] + bI[1] + Sd[mH + 4 + i] + bH[1];
      const float gin = Sd[mI + 8 + i] + bI[2];
      const float ghn = Sd[mH + 8 + i] + bH[2];
      const float rg = sigf(pr), zg = sigf(pz);
      const float ng = tanhf(gin + rg * ghn);
      const int   jj = 2 * wg + (i >> 1);
      const unsigned hu = (layer ? sH1 : sH0)[par][swzH_pos(jj)];
      const float hp = unpk(hu, i & 1);
      float hn = (1.f - zg) * ng + zg * hp;
      const bool valid = layer ? (s >= 1) : (s < N0);
      hn = valid ? hn : 0.f;
      const float v0 = __shfl(hn, 0), v1 = __shfl(hn, 1);
      const float v2 = __shfl(hn, 2), v3 = __shfl(hn, 3);
      const float w0 = __shfl(hn, 4), w1 = __shfl(hn, 5);
      const float w2 = __shfl(hn, 6), w3 = __shfl(hn, 7);
      if (lane == 0) {
        u32x4 rec0 = {pk(v0, v1), pk(v2, v3), (unsigned)s, 0u};
        u32x4 rec1 = {pk(w0, w1), pk(w2, w3), (unsigned)s, 0u};
        st_sc_v4(&g_recL0[par][wg], rec0);
        st_sc_v4(&g_recL1[par][wg], rec1);
        if (PHASE == 1) {
          if ((s & 63) == 63) {                       // sample hs0[s]
            u32x2 t2 = {rec0[0], rec0[1]};
            st_sc_v2(&g_seq2[2 * (s >> 6)][2 * wg], t2);
          }
          if (s >= 1 && ((s - 1) & 63) == 63) {       // sample hs1[s-1]
            u32x2 t2 = {rec1[0], rec1[1]};
            st_sc_v2(&g_seq2[2 * ((s - 1) >> 6) + 1][2 * wg], t2);
          }
        }
      }
    }
    // no trailing sync needed: next iteration uses the other parity buffers,
    // and its first __syncthreads orders everything.
  }

  // =======================  FC tail (phase 2, WG 0)  =======================
  if (PHASE == 2 && wg == 0) {
    // sH0[0] already holds h2_0[255] (staged at s=256). Fetch h2_1[255]
    // (stored at s=256, tag 256, slot 0).
    {
      const u32x4* a1 = &g_recL1[0][tid];
      u32x4 r1 = ld_sc_v4(a1);
      while (r1[2] != 256u) { __builtin_amdgcn_s_sleep(1); r1 = ld_sc_v4(a1); }
      sH1[0][swzH_pos(2 * tid)]     = r1[0];
      sH1[0][swzH_pos(2 * tid + 1)] = r1[1];
    }
    __syncthreads();
    if (tid < 128) {
      const int lsel = tid >> 6;        // 0: from h2_0, 1: from h2_1
      const int k = tid & 63;
      const unsigned* Hs = lsel ? sH1[0] : sH0[0];
      const float* wrow = fc1W + (size_t)k * 1024;
      float a = fc1b[k];
      for (int j2 = 0; j2 < 512; ++j2) {
        const unsigned hu = Hs[swzH_pos(j2)];
        a += unpk(hu, 0) * wrow[2 * j2] + unpk(hu, 1) * wrow[2 * j2 + 1];
      }
      sY[tid] = sigf(a);
    }
    __syncthreads();
    if (tid < 2) {
      const float* yv = sY + tid * 64;
      float a = fc2b[0];
      for (int k2 = 0; k2 < 64; ++k2) a += fc2W[k2] * yv[k2];
      out[tid] = sigf(a);
    }
  }
}

extern "C" void kernel_launch(void* const* d_in, const int* in_sizes, int n_in,
                              void* d_out, int out_size, void* d_ws, size_t ws_size,
                              hipStream_t stream) {
  (void)in_sizes; (void)n_in; (void)out_size; (void)d_ws; (void)ws_size;
  const float* x      = (const float*)d_in[0];
  const float* g1_Wi0 = (const float*)d_in[1];
  const float* g1_Wh0 = (const float*)d_in[2];
  const float* g1_bi0 = (const float*)d_in[3];
  const float* g1_bh0 = (const float*)d_in[4];
  const float* g1_Wi1 = (const float*)d_in[5];
  const float* g1_Wh1 = (const float*)d_in[6];
  const float* g1_bi1 = (const float*)d_in[7];
  const float* g1_bh1 = (const float*)d_in[8];
  const float* g2_Wi0 = (const float*)d_in[9];
  const float* g2_Wh0 = (const float*)d_in[10];
  const float* g2_bi0 = (const float*)d_in[11];
  const float* g2_bh0 = (const float*)d_in[12];
  const float* g2_Wi1 = (const float*)d_in[13];
  const float* g2_Wh1 = (const float*)d_in[14];
  const float* g2_bi1 = (const float*)d_in[15];
  const float* g2_bh1 = (const float*)d_in[16];
  const float* fc1W   = (const float*)d_in[17];
  const float* fc1b   = (const float*)d_in[18];
  const float* fc2W   = (const float*)d_in[19];
  const float* fc2b   = (const float*)d_in[20];
  float* out = (float*)d_out;

  init_recs<<<dim3(4), dim3(256), 0, stream>>>();
  gru_phase<1><<<dim3(NWG), dim3(256), 0, stream>>>(
      g1_Wh0, g1_Wi1, g1_Wh1, g1_Wi0, g1_bh0, g1_bi1, g1_bh1, g1_bi0,
      x, fc1W, fc1b, fc2W, fc2b, out);
  gru_phase<2><<<dim3(NWG), dim3(256), 0, stream>>>(
      g2_Wh0, g2_Wi1, g2_Wh1, g2_Wi0, g2_bh0, g2_bi1, g2_bh1, g2_bi0,
      x, fc1W, fc1b, fc2W, fc2b, out);
}

// Round 2
// 26788.800 us; speedup vs baseline: 1.0840x; 1.0840x over previous
//
#include <hip/hip_runtime.h>

// ---------------------------------------------------------------------------
// GRUNet: one flattened 8192-step 2-layer GRU scan (phase 1), a 256-step
// 2-layer GRU scan over sampled states (phase 2), then 2 tiny FCs -> 2 floats.
// Persistent-ish: 256 WGs (one per CU), each WG owns 4 h-elems. Cross-WG
// broadcast+sync per step via 16B {data,tag} records through L3 (sc1 ops).
// Round 2: 512 threads/WG, 48 packed-f16 weight u32 per thread -> NO scratch
// spill (round 1 had VGPR=80 < 96 needed => spilled, 928MB HBM leak).
// ---------------------------------------------------------------------------

typedef unsigned u32x4 __attribute__((ext_vector_type(4)));
typedef unsigned u32x2 __attribute__((ext_vector_type(2)));
typedef _Float16 h2_t  __attribute__((ext_vector_type(2)));

#define NWG 256

// persistent device state (re-initialized every call by init_recs)
__device__ u32x4    g_recL0[2][NWG];     // layer-0 h records: {pair0,pair1,tag,0}
__device__ u32x4    g_recL1[2][NWG];     // layer-1 h records
__device__ unsigned g_seq2[256][512];    // sampled states (f16 pairs) for gru2

// ---- f16 pack/unpack (RNE) ----
__device__ __forceinline__ unsigned pk(float a, float b) {
  unsigned short ua = __builtin_bit_cast(unsigned short, (_Float16)a);
  unsigned short ub = __builtin_bit_cast(unsigned short, (_Float16)b);
  return (unsigned)ua | ((unsigned)ub << 16);
}
__device__ __forceinline__ float unpk(unsigned u, int hi) {
  unsigned short us = (unsigned short)(hi ? (u >> 16) : (u & 0xffffu));
  return (float)__builtin_bit_cast(_Float16, us);
}

// ---- dot2: f16x2 * f16x2 + f32 ----
#if __has_builtin(__builtin_amdgcn_fdot2)
__device__ __forceinline__ float fdot2(unsigned a, unsigned b, float c) {
  return __builtin_amdgcn_fdot2(__builtin_bit_cast(h2_t, a),
                                __builtin_bit_cast(h2_t, b), c, false);
}
#else
__device__ __forceinline__ float fdot2(unsigned a, unsigned b, float c) {
  h2_t ha = __builtin_bit_cast(h2_t, a), hb = __builtin_bit_cast(h2_t, b);
  return c + (float)ha[0] * (float)hb[0] + (float)ha[1] * (float)hb[1];
}
#endif

// ---- agent-scope (coherent-at-L3) vector load/store ----
__device__ __forceinline__ u32x4 ld_sc_v4(const u32x4* p) {
  u32x4 v;
  asm volatile("global_load_dwordx4 %0, %1, off sc1\n\t"
               "s_waitcnt vmcnt(0)"
               : "=&v"(v) : "v"(p) : "memory");
  return v;
}
__device__ __forceinline__ void st_sc_v4(u32x4* p, u32x4 v) {
  asm volatile("global_store_dwordx4 %0, %1, off sc1"
               :: "v"(p), "v"(v) : "memory");
}
__device__ __forceinline__ void st_sc_v2(void* p, u32x2 v) {
  asm volatile("global_store_dwordx2 %0, %1, off sc1"
               :: "v"(p), "v"(v) : "memory");
}

// ---- fast activations (clamped; f16-noise-dominated error budget) ----
__device__ __forceinline__ float rcpf(float x) {
#if __has_builtin(__builtin_amdgcn_rcpf)
  return __builtin_amdgcn_rcpf(x);
#else
  return 1.f / x;
#endif
}
__device__ __forceinline__ float sigf(float x) {
  return rcpf(1.f + __expf(-x));
}
__device__ __forceinline__ float tanh_f(float x) {
  x = fminf(fmaxf(x, -15.f), 15.f);
  const float e = __expf(2.f * x);
  return (e - 1.f) * rcpf(e + 1.f);
}

// ---- LDS swizzles (16B-chunk XOR) ----
__device__ __forceinline__ int swzHc(int ch) { return ch ^ ((ch >> 3) & 7); } // 128-chunk bufs
__device__ __forceinline__ int swzXc(int ch) { return ch ^ ((ch >> 2) & 7); } // 64-chunk buf
__device__ __forceinline__ int swzH_pos(int idx) { return (swzHc(idx >> 2) << 2) | (idx & 3); }
__device__ __forceinline__ int swzX_pos(int idx) { return (swzXc(idx >> 2) << 2) | (idx & 3); }

__global__ void init_recs() {
  int t = blockIdx.x * blockDim.x + threadIdx.x;  // <<<4,256>>> = 1024
  u32x4 ff = {0u, 0u, 0xFFFFFFFFu, 0u};           // tag never matches a step
  if (t < 512)       g_recL0[t >> 8][t & 255] = ff;
  else               g_recL1[(t - 512) >> 8][t & 255] = ff;
}

// PHASE 1: gru1 over 8192 flat steps (layer0 input = x, 512 cols)
// PHASE 2: gru2 over 256 steps (layer0 input = g_seq2, 1024 cols) + FC tail
// Matrices: m0=Wh_l0, m1=Wi_l1, m2=Wh_l1, m3=Wi_l0.
// 8 waves: wave wv -> matrix m = wv>>1, column half kh = wv&1.
template <int PHASE>
__global__ __launch_bounds__(512, 2) void gru_phase(
    const float* __restrict__ Wm0, const float* __restrict__ Wm1,
    const float* __restrict__ Wm2, const float* __restrict__ Wm3,
    const float* __restrict__ bh0, const float* __restrict__ bi1,
    const float* __restrict__ bh1, const float* __restrict__ bi0,
    const float* __restrict__ x,
    const float* __restrict__ fc1W, const float* __restrict__ fc1b,
    const float* __restrict__ fc2W, const float* __restrict__ fc2b,
    float* __restrict__ out)
{
  constexpr int N0 = (PHASE == 1) ? 8192 : 256;   // flat steps of layer 0
  constexpr int XC = (PHASE == 1) ? 512 : 1024;   // cols of Wm3 (Wi_l0)

  const int wg   = blockIdx.x;          // owns h elements [4*wg, 4*wg+4)
  const int tid  = threadIdx.x;
  const int wv   = tid >> 6;            // wave 0..7
  const int lane = tid & 63;
  const int m    = wv >> 1;             // matrix 0..3
  const int kh   = wv & 1;              // column half
  const int g4   = lane >> 4;           // quarter-wave group
  const int q    = lane & 15;           // position in 16-lane group
  const int j0   = wg * 4;
  const bool m3s = (PHASE == 1) && (m == 3);      // the 512-col matrix

  __shared__ __attribute__((aligned(16))) unsigned sH0[2][512]; // h0[s-1], f16 pairs
  __shared__ __attribute__((aligned(16))) unsigned sH1[2][512]; // h1[s-2]
  __shared__ __attribute__((aligned(16))) unsigned sX [2][512]; // layer-0 input
  __shared__ float sD[2][96];           // partial row dots: [m*24 + kh*12 + rr]
  __shared__ float sY[128];             // FC hidden (phase 2)

  // ---- this wave's weight rows -> registers as packed f16 (48 u32 max) ----
  // group (wv,g4) handles rows rr = g4*3+t (t<3) of matrix m, half kh;
  // row rr = gate*4 + elem: global row R = (rr>>2)*1024 + j0 + (rr&3).
  // lane q covers cols [kh*cols/2 + q*(cols/32), +cols/32).
  unsigned wreg[48];
  {
    const float* Wm = (m == 0) ? Wm0 : (m == 1) ? Wm1 : (m == 2) ? Wm2 : Wm3;
    const int cols = (m == 3) ? XC : 1024;
    #pragma unroll
    for (int t = 0; t < 3; ++t) {
      const int rr = g4 * 3 + t;
      const int R  = (rr >> 2) * 1024 + j0 + (rr & 3);
      const float2* rp = (const float2*)(Wm + (size_t)R * cols + kh * (cols / 2) + q * (cols / 32));
      if (m3s) {
        #pragma unroll
        for (int p = 0; p < 8; ++p)  { float2 v = rp[p]; wreg[t * 8 + p]  = pk(v.x, v.y); }
      } else {
        #pragma unroll
        for (int p = 0; p < 16; ++p) { float2 v = rp[p]; wreg[t * 16 + p] = pk(v.x, v.y); }
      }
    }
  }

  // ---- per-lane gate biases for the combine step (wave 0, lanes 0..7) ----
  float bI[3], bH[3];
  {
    const int i = lane & 3, layer = (lane >> 2) & 1;
    const float* pbi = layer ? bi1 : bi0;
    const float* pbh = layer ? bh1 : bh0;
    #pragma unroll
    for (int g = 0; g < 3; ++g) {
      bI[g] = pbi[g * 1024 + j0 + i];
      bH[g] = pbh[g * 1024 + j0 + i];
    }
  }

  // =======================  serial scan  =======================
  for (int s = 0; s <= N0; ++s) {
    const int par = s & 1;

    // issue layer-0 input fetch early (independent of h; overlaps the poll)
    float2 xv = {0.f, 0.f};
    unsigned xs = 0;
    if (PHASE == 1) {
      if (s < N0 && tid < 256) {
        const int b = s & 63, tt = s >> 6;  // flat step s = tt*64 + b
        xv = ((const float2*)(x + (size_t)(b * 128 + tt) * 512))[tid];
      }
    } else {
      if (s < N0) xs = g_seq2[s][tid];
    }

    // poll record of step s-1 (each thread owns one record; data rides w/ tag)
    const int t2 = tid & 255;
    {
      unsigned d0 = 0, d1 = 0;
      if (s > 0) {
        const unsigned want = (unsigned)(s - 1);
        const u32x4* a = (tid < 256) ? &g_recL0[(s - 1) & 1][t2]
                                     : &g_recL1[(s - 1) & 1][t2];
        u32x4 r = ld_sc_v4(a);
        while (r[2] != want) {
          __builtin_amdgcn_s_sleep(1);
          r = ld_sc_v4(a);
        }
        d0 = r[0]; d1 = r[1];
      }
      unsigned* dst = (tid < 256) ? sH0[par] : sH1[par];
      dst[swzH_pos(2 * t2)]     = d0;
      dst[swzH_pos(2 * t2 + 1)] = d1;
    }
    if (PHASE == 1) {
      if (s < N0 && tid < 256) sX[par][swzX_pos(tid)] = pk(xv.x, xv.y);
    } else {
      if (s < N0) sX[par][swzH_pos(tid)] = xs;
    }
    __syncthreads();

    // ---- partial row dots (register weights x LDS f16 operand) ----
    float acc0 = 0.f, acc1 = 0.f, acc2 = 0.f;
    if (m3s) {                                  // Wi_l0 phase1: 512 cols
      const u32x4* Xv = (const u32x4*)sX[par];
      #pragma unroll
      for (int k = 0; k < 2; ++k) {
        u32x4 h4 = Xv[swzXc(kh * 32 + 2 * q + k)];
        #pragma unroll
        for (int u = 0; u < 4; ++u) {
          const int p = 4 * k + u;
          acc0 = fdot2(wreg[p],      h4[u], acc0);
          acc1 = fdot2(wreg[8 + p],  h4[u], acc1);
          acc2 = fdot2(wreg[16 + p], h4[u], acc2);
        }
      }
    } else {                                    // 1024-col matvecs, half-K
      const unsigned* hb = (m == 2) ? sH1[par] : (m == 3) ? sX[par] : sH0[par];
      const u32x4* Hv = (const u32x4*)hb;
      #pragma unroll
      for (int k = 0; k < 4; ++k) {
        u32x4 h4 = Hv[swzHc(kh * 64 + 4 * q + k)];
        #pragma unroll
        for (int u = 0; u < 4; ++u) {
          const int p = 4 * k + u;
          acc0 = fdot2(wreg[p],      h4[u], acc0);
          acc1 = fdot2(wreg[16 + p], h4[u], acc1);
          acc2 = fdot2(wreg[32 + p], h4[u], acc2);
        }
      }
    }
    // 16-lane reduction
    acc0 += __shfl_xor(acc0, 8, 16); acc0 += __shfl_xor(acc0, 4, 16);
    acc0 += __shfl_xor(acc0, 2, 16); acc0 += __shfl_xor(acc0, 1, 16);
    acc1 += __shfl_xor(acc1, 8, 16); acc1 += __shfl_xor(acc1, 4, 16);
    acc1 += __shfl_xor(acc1, 2, 16); acc1 += __shfl_xor(acc1, 1, 16);
    acc2 += __shfl_xor(acc2, 8, 16); acc2 += __shfl_xor(acc2, 4, 16);
    acc2 += __shfl_xor(acc2, 2, 16); acc2 += __shfl_xor(acc2, 1, 16);
    if (q < 3) {
      const float dv = (q == 0) ? acc0 : (q == 1) ? acc1 : acc2;
      sD[par][m * 24 + kh * 12 + g4 * 3 + q] = dv;
    }
    __syncthreads();

    // ---- gate combine + record store (wave 0, lanes 0..7 compute) ----
    if (wv == 0) {
      const int i = lane & 3;
      const int layer = (lane >> 2) & 1;
      const float* Sd = sD[par];
      const int mI = layer ? 1 : 3;     // Wi_l1 : Wi_l0
      const int mH = layer ? 2 : 0;     // Wh_l1 : Wh_l0
      const float dIr = Sd[mI * 24 + 0 + i] + Sd[mI * 24 + 12 + 0 + i];
      const float dIz = Sd[mI * 24 + 4 + i] + Sd[mI * 24 + 12 + 4 + i];
      const float dIn = Sd[mI * 24 + 8 + i] + Sd[mI * 24 + 12 + 8 + i];
      const float dHr = Sd[mH * 24 + 0 + i] + Sd[mH * 24 + 12 + 0 + i];
      const float dHz = Sd[mH * 24 + 4 + i] + Sd[mH * 24 + 12 + 4 + i];
      const float dHn = Sd[mH * 24 + 8 + i] + Sd[mH * 24 + 12 + 8 + i];
      const float rg = sigf(dIr + bI[0] + dHr + bH[0]);
      const float zg = sigf(dIz + bI[1] + dHz + bH[1]);
      const float ng = tanh_f(dIn + bI[2] + rg * (dHn + bH[2]));
      const int   jj = 2 * wg + (i >> 1);
      const unsigned hu = (layer ? sH1 : sH0)[par][swzH_pos(jj)];
      const float hp = unpk(hu, i & 1);
      float hn = (1.f - zg) * ng + zg * hp;
      const bool valid = layer ? (s >= 1) : (s < N0);
      hn = valid ? hn : 0.f;
      const float v0 = __shfl(hn, 0), v1 = __shfl(hn, 1);
      const float v2 = __shfl(hn, 2), v3 = __shfl(hn, 3);
      const float w0 = __shfl(hn, 4), w1 = __shfl(hn, 5);
      const float w2 = __shfl(hn, 6), w3 = __shfl(hn, 7);
      if (lane == 0) {
        u32x4 rec0 = {pk(v0, v1), pk(v2, v3), (unsigned)s, 0u};
        u32x4 rec1 = {pk(w0, w1), pk(w2, w3), (unsigned)s, 0u};
        st_sc_v4(&g_recL0[par][wg], rec0);
        st_sc_v4(&g_recL1[par][wg], rec1);
        if (PHASE == 1) {
          if ((s & 63) == 63) {                       // sample hs0[s]
            u32x2 t2v = {rec0[0], rec0[1]};
            st_sc_v2(&g_seq2[2 * (s >> 6)][2 * wg], t2v);
          }
          if (s >= 1 && ((s - 1) & 63) == 63) {       // sample hs1[s-1]
            u32x2 t2v = {rec1[0], rec1[1]};
            st_sc_v2(&g_seq2[2 * ((s - 1) >> 6) + 1][2 * wg], t2v);
          }
        }
      }
    }
    // no trailing sync: next iteration uses the other parity buffers, and its
    // first __syncthreads orders everything.
  }

  // =======================  FC tail (phase 2, WG 0)  =======================
  if (PHASE == 2 && wg == 0) {
    // sH0[0] holds h2_0[255] (staged at s=256). Fetch h2_1[255] (tag 256).
    if (tid < 256) {
      const u32x4* a1 = &g_recL1[0][tid];
      u32x4 r1 = ld_sc_v4(a1);
      while (r1[2] != 256u) { __builtin_amdgcn_s_sleep(1); r1 = ld_sc_v4(a1); }
      sH1[0][swzH_pos(2 * tid)]     = r1[0];
      sH1[0][swzH_pos(2 * tid + 1)] = r1[1];
    }
    __syncthreads();
    if (tid < 128) {
      const int lsel = tid >> 6;        // 0: from h2_0, 1: from h2_1
      const int k = tid & 63;
      const unsigned* Hs = lsel ? sH1[0] : sH0[0];
      const float* wrow = fc1W + (size_t)k * 1024;
      float a = fc1b[k];
      for (int j2 = 0; j2 < 512; ++j2) {
        const unsigned hu = Hs[swzH_pos(j2)];
        a += unpk(hu, 0) * wrow[2 * j2] + unpk(hu, 1) * wrow[2 * j2 + 1];
      }
      sY[tid] = sigf(a);
    }
    __syncthreads();
    if (tid < 2) {
      const float* yv = sY + tid * 64;
      float a = fc2b[0];
      for (int k2 = 0; k2 < 64; ++k2) a += fc2W[k2] * yv[k2];
      out[tid] = sigf(a);
    }
  }
}

extern "C" void kernel_launch(void* const* d_in, const int* in_sizes, int n_in,
                              void* d_out, int out_size, void* d_ws, size_t ws_size,
                              hipStream_t stream) {
  (void)in_sizes; (void)n_in; (void)out_size; (void)d_ws; (void)ws_size;
  const float* x      = (const float*)d_in[0];
  const float* g1_Wi0 = (const float*)d_in[1];
  const float* g1_Wh0 = (const float*)d_in[2];
  const float* g1_bi0 = (const float*)d_in[3];
  const float* g1_bh0 = (const float*)d_in[4];
  const float* g1_Wi1 = (const float*)d_in[5];
  const float* g1_Wh1 = (const float*)d_in[6];
  const float* g1_bi1 = (const float*)d_in[7];
  const float* g1_bh1 = (const float*)d_in[8];
  const float* g2_Wi0 = (const float*)d_in[9];
  const float* g2_Wh0 = (const float*)d_in[10];
  const float* g2_bi0 = (const float*)d_in[11];
  const float* g2_bh0 = (const float*)d_in[12];
  const float* g2_Wi1 = (const float*)d_in[13];
  const float* g2_Wh1 = (const float*)d_in[14];
  const float* g2_bi1 = (const float*)d_in[15];
  const float* g2_bh1 = (const float*)d_in[16];
  const float* fc1W   = (const float*)d_in[17];
  const float* fc1b   = (const float*)d_in[18];
  const float* fc2W   = (const float*)d_in[19];
  const float* fc2b   = (const float*)d_in[20];
  float* out = (float*)d_out;

  init_recs<<<dim3(4), dim3(256), 0, stream>>>();
  gru_phase<1><<<dim3(NWG), dim3(512), 0, stream>>>(
      g1_Wh0, g1_Wi1, g1_Wh1, g1_Wi0, g1_bh0, g1_bi1, g1_bh1, g1_bi0,
      x, fc1W, fc1b, fc2W, fc2b, out);
  gru_phase<2><<<dim3(NWG), dim3(512), 0, stream>>>(
      g2_Wh0, g2_Wi1, g2_Wh1, g2_Wi0, g2_bh0, g2_bi1, g2_bh1, g2_bi0,
      x, fc1W, fc1b, fc2W, fc2b, out);
}

// Round 3
// 26753.259 us; speedup vs baseline: 1.0854x; 1.0013x over previous
//
#include <hip/hip_runtime.h>

// ---------------------------------------------------------------------------
// GRUNet: one flattened 8192-step 2-layer GRU scan (phase 1), a 256-step
// 2-layer GRU scan over sampled states (phase 2), then 2 tiny FCs -> 2 floats.
// 256 WGs (one per CU), each WG owns 4 h-elems; cross-WG broadcast+sync per
// step via 16B {data,tag} records through L3 (sc1 ops).
// Round 3: weights in 12 named u32x4 SSA values (W0..W11) -- rounds 1/2 kept
// them in a C array, which the allocator sent to scratch (VGPR=48/80,
// ~888MB HBM leak, ~25MB/round L2 traffic on the serial critical path).
// Also: no s_sleep in poll loops (each iteration is already a full L3 RTT).
// ---------------------------------------------------------------------------

typedef unsigned u32x4 __attribute__((ext_vector_type(4)));
typedef unsigned u32x2 __attribute__((ext_vector_type(2)));
typedef _Float16 h2_t  __attribute__((ext_vector_type(2)));

#define NWG 256

__device__ u32x4    g_recL0[2][NWG];     // layer-0 h records: {pair0,pair1,tag,0}
__device__ u32x4    g_recL1[2][NWG];     // layer-1 h records
__device__ unsigned g_seq2[256][512];    // sampled states (f16 pairs) for gru2

// ---- f16 pack/unpack (RNE) ----
__device__ __forceinline__ unsigned pk(float a, float b) {
  unsigned short ua = __builtin_bit_cast(unsigned short, (_Float16)a);
  unsigned short ub = __builtin_bit_cast(unsigned short, (_Float16)b);
  return (unsigned)ua | ((unsigned)ub << 16);
}
__device__ __forceinline__ float unpk(unsigned u, int hi) {
  unsigned short us = (unsigned short)(hi ? (u >> 16) : (u & 0xffffu));
  return (float)__builtin_bit_cast(_Float16, us);
}

// ---- dot2: f16x2 * f16x2 + f32 ----
#if __has_builtin(__builtin_amdgcn_fdot2)
__device__ __forceinline__ float fdot2(unsigned a, unsigned b, float c) {
  return __builtin_amdgcn_fdot2(__builtin_bit_cast(h2_t, a),
                                __builtin_bit_cast(h2_t, b), c, false);
}
#else
__device__ __forceinline__ float fdot2(unsigned a, unsigned b, float c) {
  h2_t ha = __builtin_bit_cast(h2_t, a), hb = __builtin_bit_cast(h2_t, b);
  return c + (float)ha[0] * (float)hb[0] + (float)ha[1] * (float)hb[1];
}
#endif

// ---- agent-scope (coherent-at-L3) vector load/store ----
__device__ __forceinline__ u32x4 ld_sc_v4(const u32x4* p) {
  u32x4 v;
  asm volatile("global_load_dwordx4 %0, %1, off sc1\n\t"
               "s_waitcnt vmcnt(0)"
               : "=&v"(v) : "v"(p) : "memory");
  return v;
}
__device__ __forceinline__ void st_sc_v4(u32x4* p, u32x4 v) {
  asm volatile("global_store_dwordx4 %0, %1, off sc1"
               :: "v"(p), "v"(v) : "memory");
}
__device__ __forceinline__ void st_sc_v2(void* p, u32x2 v) {
  asm volatile("global_store_dwordx2 %0, %1, off sc1"
               :: "v"(p), "v"(v) : "memory");
}

// ---- fast activations (clamped; f16-noise-dominated error budget) ----
__device__ __forceinline__ float rcpf(float x) {
#if __has_builtin(__builtin_amdgcn_rcpf)
  return __builtin_amdgcn_rcpf(x);
#else
  return 1.f / x;
#endif
}
__device__ __forceinline__ float sigf(float x) {
  return rcpf(1.f + __expf(-x));
}
__device__ __forceinline__ float tanh_f(float x) {
  x = fminf(fmaxf(x, -15.f), 15.f);
  const float e = __expf(2.f * x);
  return (e - 1.f) * rcpf(e + 1.f);
}

// ---- LDS swizzles (16B-chunk XOR) ----
__device__ __forceinline__ int swzHc(int ch) { return ch ^ ((ch >> 3) & 7); } // 128-chunk bufs
__device__ __forceinline__ int swzXc(int ch) { return ch ^ ((ch >> 2) & 7); } // 64-chunk buf
__device__ __forceinline__ int swzH_pos(int idx) { return (swzHc(idx >> 2) << 2) | (idx & 3); }
__device__ __forceinline__ int swzX_pos(int idx) { return (swzXc(idx >> 2) << 2) | (idx & 3); }

__global__ void init_recs() {
  int t = blockIdx.x * blockDim.x + threadIdx.x;  // <<<4,256>>> = 1024
  u32x4 ff = {0u, 0u, 0xFFFFFFFFu, 0u};           // tag never matches a step
  if (t < 512)       g_recL0[t >> 8][t & 255] = ff;
  else               g_recL1[(t - 512) >> 8][t & 255] = ff;
}

// Fill 4 vectors (16 u32 = 32 cols) of one weight row from float4 loads.
#define LDROW16(T, A, B, C, D)                                                 \
  {                                                                            \
    const int rr = g4 * 3 + (T);                                               \
    const float4* r4 = (const float4*)(Wm + (size_t)((rr >> 2) * 1024 + j0 +   \
                       (rr & 3)) * cols + kh * (cols >> 1) + q * (cols >> 5)); \
    float4 v;                                                                  \
    v = r4[0]; A[0] = pk(v.x, v.y); A[1] = pk(v.z, v.w);                       \
    v = r4[1]; A[2] = pk(v.x, v.y); A[3] = pk(v.z, v.w);                       \
    v = r4[2]; B[0] = pk(v.x, v.y); B[1] = pk(v.z, v.w);                       \
    v = r4[3]; B[2] = pk(v.x, v.y); B[3] = pk(v.z, v.w);                       \
    v = r4[4]; C[0] = pk(v.x, v.y); C[1] = pk(v.z, v.w);                       \
    v = r4[5]; C[2] = pk(v.x, v.y); C[3] = pk(v.z, v.w);                       \
    v = r4[6]; D[0] = pk(v.x, v.y); D[1] = pk(v.z, v.w);                       \
    v = r4[7]; D[2] = pk(v.x, v.y); D[3] = pk(v.z, v.w);                       \
  }

// Fill 2 vectors (8 u32 = 16 cols) of one weight row (512-col matrix).
#define LDROW8(T, A, B)                                                        \
  {                                                                            \
    const int rr = g4 * 3 + (T);                                               \
    const float4* r4 = (const float4*)(Wm + (size_t)((rr >> 2) * 1024 + j0 +   \
                       (rr & 3)) * cols + kh * (cols >> 1) + q * (cols >> 5)); \
    float4 v;                                                                  \
    v = r4[0]; A[0] = pk(v.x, v.y); A[1] = pk(v.z, v.w);                       \
    v = r4[1]; A[2] = pk(v.x, v.y); A[3] = pk(v.z, v.w);                       \
    v = r4[2]; B[0] = pk(v.x, v.y); B[1] = pk(v.z, v.w);                       \
    v = r4[3]; B[2] = pk(v.x, v.y); B[3] = pk(v.z, v.w);                       \
  }

// One LDS chunk against 3 weight vectors (rows t=0,1,2).
#define DOTK(HSRC, IDX, A, B, C)                                               \
  {                                                                            \
    u32x4 h4 = HSRC[(IDX)];                                                    \
    acc0 = fdot2(A[0], h4[0], acc0); acc0 = fdot2(A[1], h4[1], acc0);          \
    acc0 = fdot2(A[2], h4[2], acc0); acc0 = fdot2(A[3], h4[3], acc0);          \
    acc1 = fdot2(B[0], h4[0], acc1); acc1 = fdot2(B[1], h4[1], acc1);          \
    acc1 = fdot2(B[2], h4[2], acc1); acc1 = fdot2(B[3], h4[3], acc1);          \
    acc2 = fdot2(C[0], h4[0], acc2); acc2 = fdot2(C[1], h4[1], acc2);          \
    acc2 = fdot2(C[2], h4[2], acc2); acc2 = fdot2(C[3], h4[3], acc2);          \
  }

// PHASE 1: gru1 over 8192 flat steps (layer0 input = x, 512 cols)
// PHASE 2: gru2 over 256 steps (layer0 input = g_seq2, 1024 cols) + FC tail
// Matrices: m0=Wh_l0, m1=Wi_l1, m2=Wh_l1, m3=Wi_l0.
// 8 waves: wave wv -> matrix m = wv>>1, column half kh = wv&1.
template <int PHASE>
__global__ __launch_bounds__(512, 2) void gru_phase(
    const float* __restrict__ Wm0, const float* __restrict__ Wm1,
    const float* __restrict__ Wm2, const float* __restrict__ Wm3,
    const float* __restrict__ bh0, const float* __restrict__ bi1,
    const float* __restrict__ bh1, const float* __restrict__ bi0,
    const float* __restrict__ x,
    const float* __restrict__ fc1W, const float* __restrict__ fc1b,
    const float* __restrict__ fc2W, const float* __restrict__ fc2b,
    float* __restrict__ out)
{
  constexpr int N0 = (PHASE == 1) ? 8192 : 256;   // flat steps of layer 0
  constexpr int XC = (PHASE == 1) ? 512 : 1024;   // cols of Wm3 (Wi_l0)

  const int wg   = blockIdx.x;          // owns h elements [4*wg, 4*wg+4)
  const int tid  = threadIdx.x;
  const int wv   = tid >> 6;            // wave 0..7
  const int lane = tid & 63;
  const int m    = wv >> 1;             // matrix 0..3
  const int kh   = wv & 1;              // column half
  const int g4   = lane >> 4;           // quarter-wave group
  const int q    = lane & 15;           // position in 16-lane group
  const int j0   = wg * 4;
  const bool m3s = (PHASE == 1) && (m == 3);      // the 512-col matrix

  __shared__ __attribute__((aligned(16))) unsigned sH0[2][512]; // h0[s-1], f16 pairs
  __shared__ __attribute__((aligned(16))) unsigned sH1[2][512]; // h1[s-2]
  __shared__ __attribute__((aligned(16))) unsigned sX [2][512]; // layer-0 input
  __shared__ float sD[2][96];           // partial row dots: [m*24 + kh*12 + rr]
  __shared__ float sY[128];             // FC hidden (phase 2)

  // ---- this wave's weight rows -> 12 named u32x4 SSA values (no alloca) ----
  // group (wv,g4) handles rows rr = g4*3+t (t<3) of matrix m, half kh;
  // row rr = gate*4 + elem: global row R = (rr>>2)*1024 + j0 + (rr&3).
  // lane q covers cols [kh*cols/2 + q*(cols/32), +cols/32).
  u32x4 W0{}, W1{}, W2{}, W3{}, W4{}, W5{}, W6{}, W7{}, W8{}, W9{}, W10{}, W11{};
  {
    const float* Wm = (m == 0) ? Wm0 : (m == 1) ? Wm1 : (m == 2) ? Wm2 : Wm3;
    const int cols = (m == 3) ? XC : 1024;
    if (m3s) {
      // row t -> vectors {2t, 2t+1}
      LDROW8(0, W0, W1);
      LDROW8(1, W2, W3);
      LDROW8(2, W4, W5);
    } else {
      // row t -> vectors {4t .. 4t+3}; dot uses (W0..3 | W4..7 | W8..11) per k
      LDROW16(0, W0, W4, W8,  W2);   // placeholder order fixed below
      // NOTE: careful mapping -- see DOTK usage: acc0 needs row0 = wreg[0..15]
      // => vectors indexed k (chunk) must be row-major. Reload correctly:
      LDROW16(0, W0, W1, W2,  W3);
      LDROW16(1, W4, W5, W6,  W7);
      LDROW16(2, W8, W9, W10, W11);
    }
  }

  // ---- per-lane gate biases for the combine step (wave 0, lanes 0..7) ----
  float bI0, bI1, bI2, bH0v, bH1v, bH2v;
  {
    const int i = lane & 3, layer = (lane >> 2) & 1;
    const float* pbi = layer ? bi1 : bi0;
    const float* pbh = layer ? bh1 : bh0;
    bI0 = pbi[0 * 1024 + j0 + i]; bI1 = pbi[1 * 1024 + j0 + i]; bI2 = pbi[2 * 1024 + j0 + i];
    bH0v = pbh[0 * 1024 + j0 + i]; bH1v = pbh[1 * 1024 + j0 + i]; bH2v = pbh[2 * 1024 + j0 + i];
  }

  // =======================  serial scan  =======================
  for (int s = 0; s <= N0; ++s) {
    const int par = s & 1;

    // issue layer-0 input fetch early (independent of h; overlaps the poll)
    float2 xv = {0.f, 0.f};
    unsigned xs = 0;
    if (PHASE == 1) {
      if (s < N0 && tid < 256) {
        const int b = s & 63, tt = s >> 6;  // flat step s = tt*64 + b
        xv = ((const float2*)(x + (size_t)(b * 128 + tt) * 512))[tid];
      }
    } else {
      if (s < N0) xs = g_seq2[s][tid];
    }

    // poll record of step s-1 (each thread owns one record; data rides w/ tag)
    const int t2 = tid & 255;
    {
      unsigned d0 = 0, d1 = 0;
      if (s > 0) {
        const unsigned want = (unsigned)(s - 1);
        const u32x4* a = (tid < 256) ? &g_recL0[(s - 1) & 1][t2]
                                     : &g_recL1[(s - 1) & 1][t2];
        u32x4 r = ld_sc_v4(a);
        while (r[2] != want) r = ld_sc_v4(a);
        d0 = r[0]; d1 = r[1];
      }
      unsigned* dst = (tid < 256) ? sH0[par] : sH1[par];
      dst[swzH_pos(2 * t2)]     = d0;
      dst[swzH_pos(2 * t2 + 1)] = d1;
    }
    if (PHASE == 1) {
      if (s < N0 && tid < 256) sX[par][swzX_pos(tid)] = pk(xv.x, xv.y);
    } else {
      if (s < N0) sX[par][swzH_pos(tid)] = xs;
    }
    __syncthreads();

    // ---- partial row dots (register weights x LDS f16 operand) ----
    float acc0 = 0.f, acc1 = 0.f, acc2 = 0.f;
    if (m3s) {                                  // Wi_l0 phase1: 512 cols
      const u32x4* Xv = (const u32x4*)sX[par];
      const int base = kh * 32 + 2 * q;
      // row t -> vectors {2t,2t+1}; chunk k selects vector 2t+k
      DOTK(Xv, swzXc(base + 0), W0, W2, W4);
      DOTK(Xv, swzXc(base + 1), W1, W3, W5);
    } else {                                    // 1024-col matvecs, half-K
      const unsigned* hb = (m == 2) ? sH1[par] : (m == 3) ? sX[par] : sH0[par];
      const u32x4* Hv = (const u32x4*)hb;
      const int base = kh * 64 + 4 * q;
      DOTK(Hv, swzHc(base + 0), W0, W4, W8);
      DOTK(Hv, swzHc(base + 1), W1, W5, W9);
      DOTK(Hv, swzHc(base + 2), W2, W6, W10);
      DOTK(Hv, swzHc(base + 3), W3, W7, W11);
    }
    // 16-lane reduction
    acc0 += __shfl_xor(acc0, 8, 16); acc0 += __shfl_xor(acc0, 4, 16);
    acc0 += __shfl_xor(acc0, 2, 16); acc0 += __shfl_xor(acc0, 1, 16);
    acc1 += __shfl_xor(acc1, 8, 16); acc1 += __shfl_xor(acc1, 4, 16);
    acc1 += __shfl_xor(acc1, 2, 16); acc1 += __shfl_xor(acc1, 1, 16);
    acc2 += __shfl_xor(acc2, 8, 16); acc2 += __shfl_xor(acc2, 4, 16);
    acc2 += __shfl_xor(acc2, 2, 16); acc2 += __shfl_xor(acc2, 1, 16);
    if (q < 3) {
      const float dv = (q == 0) ? acc0 : (q == 1) ? acc1 : acc2;
      sD[par][m * 24 + kh * 12 + g4 * 3 + q] = dv;
    }
    __syncthreads();

    // ---- gate combine + record store (wave 0, lanes 0..7 compute) ----
    if (wv == 0) {
      const int i = lane & 3;
      const int layer = (lane >> 2) & 1;
      const float* Sd = sD[par];
      const int mI = layer ? 1 : 3;     // Wi_l1 : Wi_l0
      const int mH = layer ? 2 : 0;     // Wh_l1 : Wh_l0
      const float dIr = Sd[mI * 24 + 0 + i] + Sd[mI * 24 + 12 + 0 + i];
      const float dIz = Sd[mI * 24 + 4 + i] + Sd[mI * 24 + 12 + 4 + i];
      const float dIn = Sd[mI * 24 + 8 + i] + Sd[mI * 24 + 12 + 8 + i];
      const float dHr = Sd[mH * 24 + 0 + i] + Sd[mH * 24 + 12 + 0 + i];
      const float dHz = Sd[mH * 24 + 4 + i] + Sd[mH * 24 + 12 + 4 + i];
      const float dHn = Sd[mH * 24 + 8 + i] + Sd[mH * 24 + 12 + 8 + i];
      const float rg = sigf(dIr + bI0 + dHr + bH0v);
      const float zg = sigf(dIz + bI1 + dHz + bH1v);
      const float ng = tanh_f(dIn + bI2 + rg * (dHn + bH2v));
      const int   jj = 2 * wg + (i >> 1);
      const unsigned hu = (layer ? sH1 : sH0)[par][swzH_pos(jj)];
      const float hp = unpk(hu, i & 1);
      float hn = (1.f - zg) * ng + zg * hp;
      const bool valid = layer ? (s >= 1) : (s < N0);
      hn = valid ? hn : 0.f;
      const float v0 = __shfl(hn, 0), v1 = __shfl(hn, 1);
      const float v2 = __shfl(hn, 2), v3 = __shfl(hn, 3);
      const float w0 = __shfl(hn, 4), w1 = __shfl(hn, 5);
      const float w2 = __shfl(hn, 6), w3 = __shfl(hn, 7);
      if (lane == 0) {
        u32x4 rec0 = {pk(v0, v1), pk(v2, v3), (unsigned)s, 0u};
        u32x4 rec1 = {pk(w0, w1), pk(w2, w3), (unsigned)s, 0u};
        st_sc_v4(&g_recL0[par][wg], rec0);
        st_sc_v4(&g_recL1[par][wg], rec1);
        if (PHASE == 1) {
          if ((s & 63) == 63) {                       // sample hs0[s]
            u32x2 t2v = {rec0[0], rec0[1]};
            st_sc_v2(&g_seq2[2 * (s >> 6)][2 * wg], t2v);
          }
          if (s >= 1 && ((s - 1) & 63) == 63) {       // sample hs1[s-1]
            u32x2 t2v = {rec1[0], rec1[1]};
            st_sc_v2(&g_seq2[2 * ((s - 1) >> 6) + 1][2 * wg], t2v);
          }
        }
      }
    }
    // no trailing sync: next iteration uses the other parity buffers, and its
    // first __syncthreads orders everything.
  }

  // =======================  FC tail (phase 2, WG 0)  =======================
  if (PHASE == 2 && wg == 0) {
    // sH0[0] holds h2_0[255] (staged at s=256). Fetch h2_1[255] (tag 256).
    if (tid < 256) {
      const u32x4* a1 = &g_recL1[0][tid];
      u32x4 r1 = ld_sc_v4(a1);
      while (r1[2] != 256u) r1 = ld_sc_v4(a1);
      sH1[0][swzH_pos(2 * tid)]     = r1[0];
      sH1[0][swzH_pos(2 * tid + 1)] = r1[1];
    }
    __syncthreads();
    if (tid < 128) {
      const int lsel = tid >> 6;        // 0: from h2_0, 1: from h2_1
      const int k = tid & 63;
      const unsigned* Hs = lsel ? sH1[0] : sH0[0];
      const float* wrow = fc1W + (size_t)k * 1024;
      float a = fc1b[k];
      for (int j2 = 0; j2 < 512; ++j2) {
        const unsigned hu = Hs[swzH_pos(j2)];
        a += unpk(hu, 0) * wrow[2 * j2] + unpk(hu, 1) * wrow[2 * j2 + 1];
      }
      sY[tid] = sigf(a);
    }
    __syncthreads();
    if (tid < 2) {
      const float* yv = sY + tid * 64;
      float a = fc2b[0];
      for (int k2 = 0; k2 < 64; ++k2) a += fc2W[k2] * yv[k2];
      out[tid] = sigf(a);
    }
  }
}

extern "C" void kernel_launch(void* const* d_in, const int* in_sizes, int n_in,
                              void* d_out, int out_size, void* d_ws, size_t ws_size,
                              hipStream_t stream) {
  (void)in_sizes; (void)n_in; (void)out_size; (void)d_ws; (void)ws_size;
  const float* x      = (const float*)d_in[0];
  const float* g1_Wi0 = (const float*)d_in[1];
  const float* g1_Wh0 = (const float*)d_in[2];
  const float* g1_bi0 = (const float*)d_in[3];
  const float* g1_bh0 = (const float*)d_in[4];
  const float* g1_Wi1 = (const float*)d_in[5];
  const float* g1_Wh1 = (const float*)d_in[6];
  const float* g1_bi1 = (const float*)d_in[7];
  const float* g1_bh1 = (const float*)d_in[8];
  const float* g2_Wi0 = (const float*)d_in[9];
  const float* g2_Wh0 = (const float*)d_in[10];
  const float* g2_bi0 = (const float*)d_in[11];
  const float* g2_bh0 = (const float*)d_in[12];
  const float* g2_Wi1 = (const float*)d_in[13];
  const float* g2_Wh1 = (const float*)d_in[14];
  const float* g2_bi1 = (const float*)d_in[15];
  const float* g2_bh1 = (const float*)d_in[16];
  const float* fc1W   = (const float*)d_in[17];
  const float* fc1b   = (const float*)d_in[18];
  const float* fc2W   = (const float*)d_in[19];
  const float* fc2b   = (const float*)d_in[20];
  float* out = (float*)d_out;

  init_recs<<<dim3(4), dim3(256), 0, stream>>>();
  gru_phase<1><<<dim3(NWG), dim3(512), 0, stream>>>(
      g1_Wh0, g1_Wi1, g1_Wh1, g1_Wi0, g1_bh0, g1_bi1, g1_bh1, g1_bi0,
      x, fc1W, fc1b, fc2W, fc2b, out);
  gru_phase<2><<<dim3(NWG), dim3(512), 0, stream>>>(
      g2_Wh0, g2_Wi1, g2_Wh1, g2_Wi0, g2_bh0, g2_bi1, g2_bh1, g2_bi0,
      x, fc1W, fc1b, fc2W, fc2b, out);
}